// Round 17
// baseline (831.452 us; speedup 1.0000x reference)
//
#include <hip/hip_runtime.h>
#include <stdint.h>

#define NN 10000
#define NE 48000
#define DIM 768
#define NH 4
#define NL 4
#define NR 3
#define HD 3072
#define NPAD 10240   // 80*128
#define NRD (NR*DIM) // 2304
#define NRDE 2432    // 19*128 (T3 cols + 128 alpha cols)
#define SCN (NR*NN)  // 30000
#define SCB ((SCN+255)/256) // 118

typedef __attribute__((ext_vector_type(8))) short bf16x8;
typedef __attribute__((ext_vector_type(4))) float f32x4;

__device__ __forceinline__ unsigned short f2b(float f){
  union {float f; unsigned u;} v; v.f=f;
  unsigned r = v.u + 0x7FFFu + ((v.u>>16)&1u);
  return (unsigned short)(r>>16);
}
__device__ __forceinline__ float b2f(unsigned short b){
  union {unsigned u; float f;} v; v.u = ((unsigned)b)<<16; return v.f;
}

__device__ __forceinline__ void gl_lds16(const void* g, void* l){
  __builtin_amdgcn_global_load_lds(
    reinterpret_cast<const __attribute__((address_space(1))) uint32_t*>(reinterpret_cast<uintptr_t>(g)),
    reinterpret_cast<__attribute__((address_space(3))) uint32_t*>(reinterpret_cast<uintptr_t>(l)),
    16, 0, 0);
}

// ====== 128x128 8-wave GEMM, 2-barrier/tile, symmetric full-tile prefetch ======
// C[m][n] = sum_k A[m][k]*Bt[n][k]; A,Bt bf16 K-contiguous; f32 accum.
// Ledger: after tile t's read-barrier, issue ALL of tile t+2 into slot t&1.
// Steady wait vmcnt(4) (tile t+1 in flight). Every chunk gets ~2 tiles slack.
// MODE: 0 = f32 out (+bias), 1 = bf16 out (+bias), 2 = bf16 relu (+bias),
//       3 = fused update: w=relu(RH+acc+bscale*bias); C=w(f32), C2=bf16(w)
//       4 = T3+alpha: col<NRD -> bf16 C; col-NRD<24 -> f32 scatter to PA/PD
template<int MODE>
__global__ __launch_bounds__(512, 4)
void gemmU(const unsigned short* __restrict__ A, const unsigned short* __restrict__ Bt,
           void* __restrict__ C, unsigned short* __restrict__ C2,
           const float* __restrict__ RH, const float* __restrict__ bias, float bscale,
           int K, int Mvalid, int ldc,
           float* __restrict__ PA, float* __restrict__ PD)
{
  constexpr int NB     = 2;
  constexpr int ABYTES = 16384;
  constexpr int SLOT   = 32768;
  __shared__ char lds2[2*SLOT];            // 64 KB -> 2 blocks/CU

  const int tid = threadIdx.x;
  const int lane = tid & 63;
  const int wv = tid >> 6;
  const int wr = wv >> 2;
  const int wc = wv & 3;
  const int fr = lane & 15;
  const int fs = lane >> 4;

  int bx, by;
  {
    int fid = blockIdx.y * gridDim.x + blockIdx.x;
    if ((gridDim.y & 7) == 0){
      int xcd = fid & 7, slot = fid >> 3;
      bx = slot % gridDim.x;
      by = (slot / gridDim.x) * 8 + xcd;
    } else { bx = blockIdx.x; by = blockIdx.y; }
  }

  const unsigned short* Ag = A + (size_t)by * 128 * K;
  const unsigned short* Bg = Bt + (size_t)bx * 128 * K;
  const int T = K >> 6;

  f32x4 acc[4][NB];
  #pragma unroll
  for (int i=0;i<4;i++)
    #pragma unroll
    for (int j=0;j<NB;j++) acc[i][j] = (f32x4){0.f,0.f,0.f,0.f};

  auto stage = [&](int t2, int c){
    char* region = lds2 + (t2 & 1) * SLOT;
    const unsigned short* G = Ag;
    int off = c * 8192 + tid * 16;
    if (c >= 2){ G = Bg; off -= ABYTES; region += ABYTES; }
    int row = off >> 7;
    int srcslot = ((off >> 4) & 7) ^ (row & 7);
    gl_lds16((const char*)(G + (size_t)row * K + (size_t)t2 * 64) + (srcslot << 4),
             region + off);
  };

  // prologue: tile0 (slot0) fully, tile1 (slot1) fully -> 8 outstanding
  #pragma unroll
  for (int c=0;c<4;c++) stage(0,c);
  __builtin_amdgcn_sched_barrier(0);
  #pragma unroll
  for (int c=0;c<4;c++) stage(1,c);
  __builtin_amdgcn_sched_barrier(0);

  for (int t=0; t<T; ++t){
    const char* As_ = lds2 + (t&1)*SLOT;
    const char* Bs_ = As_ + ABYTES;

    if (t < T-1) asm volatile("s_waitcnt vmcnt(4)" ::: "memory");
    else         asm volatile("s_waitcnt vmcnt(0)" ::: "memory");
    __builtin_amdgcn_s_barrier();

    // issue all 12 fragment reads
    bf16x8 a[4][2], b[NB][2];
    #pragma unroll
    for (int ni=0; ni<NB; ni++){
      const int row = wc*32 + ni*16 + fr;
      #pragma unroll
      for (int ks=0; ks<2; ks++){
        const int bo = row*128 + ((((ks<<2)+fs) ^ (row&7))<<4);
        b[ni][ks] = *(const bf16x8*)(Bs_ + bo);
      }
    }
    #pragma unroll
    for (int mi=0; mi<4; mi++){
      const int row = wr*64 + mi*16 + fr;
      #pragma unroll
      for (int ks=0; ks<2; ks++){
        const int bo = row*128 + ((((ks<<2)+fs) ^ (row&7))<<4);
        a[mi][ks] = *(const bf16x8*)(As_ + bo);
      }
    }
    asm volatile("s_waitcnt lgkmcnt(0)" ::: "memory");
    __builtin_amdgcn_s_barrier();            // all waves done reading this slot

    if (t+2 < T){                            // full tile t+2 into freed slot
      stage(t+2,0); stage(t+2,1); stage(t+2,2); stage(t+2,3);
    }
    __builtin_amdgcn_sched_barrier(0);

    __builtin_amdgcn_s_setprio(1);
    #pragma unroll
    for (int mi=0; mi<4; mi++)
      #pragma unroll
      for (int ni=0; ni<NB; ni++)
        #pragma unroll
        for (int ks=0; ks<2; ks++)
          acc[mi][ni] = __builtin_amdgcn_mfma_f32_16x16x32_bf16(
              a[mi][ks], b[ni][ks], acc[mi][ni], 0,0,0);
    __builtin_amdgcn_s_setprio(0);
  }

  const int cr = (lane>>4)<<2, cc = lane&15;
  #pragma unroll
  for (int mi=0; mi<4; mi++){
    #pragma unroll
    for (int ni=0; ni<NB; ni++){
      const int col = bx*128 + wc*32 + ni*16 + cc;
      const float bv = bias ? bscale*bias[col] : 0.0f;
      #pragma unroll
      for (int j=0; j<4; j++){
        const int row = by*128 + wr*64 + mi*16 + cr + j;
        if (row < Mvalid){
          const size_t o = (size_t)row*ldc + col;
          float v = acc[mi][ni][j] + bv;
          if (MODE==2) v = v>0.f?v:0.f;
          if (MODE==0)      ((float*)C)[o] = v;
          else if (MODE==1 || MODE==2) ((unsigned short*)C)[o] = f2b(v);
          else if (MODE==3){
            float w = RH[o] + v;
            w = w>0.f?w:0.f;
            ((float*)C)[o] = w; C2[o] = f2b(w);
          } else { // MODE==4
            if (col < NRD) ((unsigned short*)C)[o] = f2b(v);
            else {
              int jj = col - NRD;
              if (jj < 24){
                int rr = jj>>3, hh = (jj>>1)&3, ss = jj&1;
                float* dst = ss ? PD : PA;
                dst[((size_t)rr*NN + row)*NH + hh] = v;
              }
            }
          }
        }
      }
    }
  }
}

// ---------------- misc elementwise / precompute --------------------------------
__global__ void k_init(const float* __restrict__ nf, float* __restrict__ h, unsigned short* __restrict__ hb){
  for (size_t i = (size_t)blockIdx.x*256+threadIdx.x; i < (size_t)NPAD*DIM; i += (size_t)gridDim.x*256){
    float v = (i < (size_t)NN*DIM) ? nf[i] : 0.0f;
    h[i]=v; hb[i]=f2b(v);
  }
}
__global__ void k_transpose(const float* __restrict__ in, unsigned short* __restrict__ out,
                            int rows, int cols, long in_bs, long out_bs){
  __shared__ float tile[32][33];
  int b = blockIdx.z;
  int r0 = blockIdx.y*32, c0 = blockIdx.x*32;
  int tx = threadIdx.x & 31, ty = threadIdx.x >> 5;
  const float* ip = in + (size_t)b*in_bs;
  unsigned short* op = out + (size_t)b*out_bs;
  #pragma unroll
  for (int i=ty;i<32;i+=8) tile[i][tx] = ip[(size_t)(r0+i)*cols + c0+tx];
  __syncthreads();
  #pragma unroll
  for (int i=ty;i<32;i+=8) op[(size_t)(c0+i)*rows + r0+tx] = f2b(tile[tx][i]);
}
// GATWS[l][d][h*768+q] = 0.25 * gat_W[l][q][h*768+d]
__global__ void k_gatws(const float* __restrict__ gat_W, unsigned short* __restrict__ out){
  __shared__ float tile[32][33];
  int z = blockIdx.z; int l = z>>2, h = z&3;
  size_t base = (size_t)l*DIM*HD + (size_t)h*DIM;
  int r0 = blockIdx.y*32, c0 = blockIdx.x*32;
  int tx = threadIdx.x & 31, ty = threadIdx.x >> 5;
  #pragma unroll
  for (int i=ty;i<32;i+=8) tile[i][tx] = gat_W[base + (size_t)(r0+i)*HD + c0+tx];
  __syncthreads();
  #pragma unroll
  for (int i=ty;i<32;i+=8) out[base + (size_t)(c0+i)*HD + r0+tx] = f2b(0.25f*tile[tx][i]);
}

// attention-weight precompute
__global__ __launch_bounds__(256) void k_vsrc(const float* __restrict__ gat_W, const float* __restrict__ a_src,
                       const float* __restrict__ a_dst, float* __restrict__ vs, float* __restrict__ vd){
  int gw = blockIdx.x*4 + (threadIdx.x>>6);
  if (gw >= NL*DIM) return;
  int l = gw/DIM;
  int lane = threadIdx.x & 63;
  const float* grow = gat_W + (size_t)gw*HD;
  #pragma unroll
  for (int h=0;h<NH;h++){
    const float* asr = a_src + ((size_t)l*NH + h)*DIM;
    const float* adr = a_dst + ((size_t)l*NH + h)*DIM;
    float s=0.f,d=0.f;
    for (int dd=lane; dd<DIM; dd+=64){
      float gv = grow[h*DIM+dd];
      s += gv*asr[dd]; d += gv*adr[dd];
    }
    #pragma unroll
    for (int o=32;o>=1;o>>=1){ s += __shfl_xor(s,o,64); d += __shfl_xor(d,o,64); }
    if (lane==0){ vs[(size_t)gw*NH+h]=s; vd[(size_t)gw*NH+h]=d; }
  }
}
__global__ __launch_bounds__(256) void k_wa(const float* __restrict__ rel_W, const float* __restrict__ vs,
                     const float* __restrict__ vd, float* __restrict__ was, float* __restrict__ wad){
  int gw = blockIdx.x*4 + (threadIdx.x>>6);
  if (gw >= NL*NR*DIM) return;
  int lr = gw/DIM, k = gw%DIM;
  int l = lr/NR, r = lr%NR;
  int lane = threadIdx.x & 63;
  const float* wrow = rel_W + ((size_t)r*DIM + k)*DIM;
  float s0=0,s1=0,s2=0,s3=0,d0=0,d1=0,d2=0,d3=0;
  for (int q=lane; q<DIM; q+=64){
    float w = wrow[q];
    const float4 v1 = *(const float4*)(vs + ((size_t)l*DIM+q)*NH);
    const float4 v2 = *(const float4*)(vd + ((size_t)l*DIM+q)*NH);
    s0+=w*v1.x; s1+=w*v1.y; s2+=w*v1.z; s3+=w*v1.w;
    d0+=w*v2.x; d1+=w*v2.y; d2+=w*v2.z; d3+=w*v2.w;
  }
  #pragma unroll
  for (int o=32;o>=1;o>>=1){
    s0+=__shfl_xor(s0,o,64); s1+=__shfl_xor(s1,o,64); s2+=__shfl_xor(s2,o,64); s3+=__shfl_xor(s3,o,64);
    d0+=__shfl_xor(d0,o,64); d1+=__shfl_xor(d1,o,64); d2+=__shfl_xor(d2,o,64); d3+=__shfl_xor(d3,o,64);
  }
  if (lane==0){
    float4* ps = (float4*)(was + (size_t)gw*NH); *ps = make_float4(s0,s1,s2,s3);
    float4* pd = (float4*)(wad + (size_t)gw*NH); *pd = make_float4(d0,d1,d2,d3);
  }
}
__global__ void k_bsd(const float* __restrict__ rel_b, const float* __restrict__ vs, const float* __restrict__ vd,
                      float* __restrict__ bs, float* __restrict__ bd){
  int t = threadIdx.x; if (t >= NL*NR*NH) return;
  int l = t/(NR*NH), r = (t/NH)%NR, h = t%NH;
  float s=0.f,d=0.f;
  for (int q=0;q<DIM;q++){
    float b = rel_b[r*DIM+q];
    s += b*vs[((size_t)l*DIM+q)*NH+h];
    d += b*vd[((size_t)l*DIM+q)*NH+h];
  }
  bs[t]=s; bd[t]=d;
}
// BEXT alpha rows: BEXT[l][NRD+j][k], j<24 -> (s?WAD:WAS)[l,r,k,h]; j>=24 -> 0
__global__ void k_bext(const float* __restrict__ WAS, const float* __restrict__ WAD,
                       unsigned short* __restrict__ BEXT){
  int idx = blockIdx.x*256+threadIdx.x;
  if (idx >= NL*128*DIM) return;
  int l = idx/(128*DIM);
  int rem = idx - l*(128*DIM);
  int j = rem/DIM, k = rem%DIM;
  float v = 0.f;
  if (j < 24){
    int r = j>>3, h = (j>>1)&3, s = j&1;
    const float* src = s ? WAD : WAS;
    v = src[(((size_t)l*NR+r)*DIM + k)*NH + h];
  }
  BEXT[(size_t)l*NRDE*DIM + (size_t)(NRD+j)*DIM + k] = f2b(v);
}
// BIASX[l][c]: c<NRD -> rel_b[c]; NRD+j (j<24) -> (s?BD:BS)[l,r,h]; else 0
__global__ void k_biasx(const float* __restrict__ rel_b, const float* __restrict__ BS,
                        const float* __restrict__ BD, float* __restrict__ BIASX){
  int idx = blockIdx.x*256+threadIdx.x;
  if (idx >= NL*NRDE) return;
  int l = idx/NRDE, c = idx%NRDE;
  float v = 0.f;
  if (c < NRD) v = rel_b[c];
  else {
    int j = c-NRD;
    if (j < 24){
      int r = j>>3, h = (j>>1)&3, s = j&1;
      v = (s ? BD : BS)[(l*NR+r)*NH + h];
    }
  }
  BIASX[idx] = v;
}

// ---------------- CSR build ----------------------------------------------------
__global__ void k_count(const int* __restrict__ et, const int* __restrict__ ei, int* __restrict__ counts){
  int e = blockIdx.x*256+threadIdx.x; if (e>=NE) return;
  atomicAdd(&counts[et[e]*NN + ei[NE+e]], 1);
}
__global__ void k_scan1(const int* __restrict__ counts, int* __restrict__ excl, int* __restrict__ part){
  __shared__ int tmp[256];
  int b = blockIdx.x, t = threadIdx.x, idx = b*256+t;
  int v = (idx<SCN)? counts[idx] : 0;
  tmp[t]=v; __syncthreads();
  #pragma unroll
  for (int off=1; off<256; off<<=1){
    int x = (t>=off)? tmp[t-off] : 0;
    __syncthreads(); tmp[t]+=x; __syncthreads();
  }
  if (idx<SCN) excl[idx] = tmp[t]-v;
  if (t==255) part[b] = tmp[255];
}
__global__ void k_scan2(int* __restrict__ part){
  if (threadIdx.x==0){
    int c=0;
    for (int i=0;i<SCB;i++){ int v=part[i]; part[i]=c; c+=v; }
    part[SCB]=c;
  }
}
__global__ void k_scan3(int* __restrict__ rs, const int* __restrict__ part, int* __restrict__ cursor){
  int b = blockIdx.x, idx = b*256+threadIdx.x;
  if (idx<SCN){
    int e = rs[idx] + part[b];
    rs[idx]=e; cursor[idx]=e;
  }
  if (idx==0) rs[SCN] = part[SCB];
}
__global__ void k_fill(const int* __restrict__ et, const int* __restrict__ ei, int* __restrict__ cursor,
                       int* __restrict__ csrs, int* __restrict__ csre){
  int e = blockIdx.x*256+threadIdx.x; if (e>=NE) return;
  int pos = atomicAdd(&cursor[et[e]*NN + ei[NE+e]], 1);
  csrs[pos] = ei[e];
  csre[pos] = e;
}

// ---------------- fused softmax + aggregate ------------------------------------
// Z[n][h*768+q] = sum_r inv_{r,h} * ( p_self t_r[n][q] + sum_e p_eh t_r[s][q] )
__global__ __launch_bounds__(256) void k_aggz(const unsigned short* __restrict__ T3,
    const float* __restrict__ aS, const float* __restrict__ aD,
    const int* __restrict__ row_start, const int* __restrict__ csrs,
    unsigned short* __restrict__ Z)
{
  int n = blockIdx.x, t = threadIdx.x;
  float z[3][NH];
  #pragma unroll
  for (int u=0;u<3;u++)
    #pragma unroll
    for (int hh=0;hh<NH;hh++) z[u][hh]=0.f;

  for (int r=0;r<NR;r++){
    int rn = r*NN+n;
    const float4 adv = *(const float4*)(aD + (size_t)rn*NH);
    const float4 asv = *(const float4*)(aS + (size_t)rn*NH);
    const float ad_n[NH] = {adv.x, adv.y, adv.z, adv.w};
    float es[NH], m[NH];
    {
      const float as_n[NH] = {asv.x, asv.y, asv.z, asv.w};
      #pragma unroll
      for (int hh=0;hh<NH;hh++){
        float e = as_n[hh] + ad_n[hh]; e = e>0.f?e:0.2f*e;
        es[hh]=e; m[hh]=e;
      }
    }
    int beg = row_start[rn], end = row_start[rn+1];
    for (int p=beg;p<end;p++){
      int s = csrs[p];
      const float4 av = *(const float4*)(aS + ((size_t)r*NN+s)*NH);
      const float ash[NH] = {av.x, av.y, av.z, av.w};
      #pragma unroll
      for (int hh=0;hh<NH;hh++){
        float e = ash[hh] + ad_n[hh]; e = e>0.f?e:0.2f*e;
        m[hh] = fmaxf(m[hh], e);
      }
    }
    float den[NH], acc[3][NH];
    const unsigned short* tn = T3 + (size_t)n*NRD + r*DIM;
    {
      float ps[NH];
      #pragma unroll
      for (int hh=0;hh<NH;hh++){ ps[hh]=__expf(es[hh]-m[hh]); den[hh]=ps[hh]; }
      #pragma unroll
      for (int u=0;u<3;u++){
        float tv = b2f(tn[t+256*u]);
        #pragma unroll
        for (int hh=0;hh<NH;hh++) acc[u][hh] = ps[hh]*tv;
      }
    }
    for (int p=beg;p<end;p++){
      int s = csrs[p];
      const float4 av = *(const float4*)(aS + ((size_t)r*NN+s)*NH);
      const float ash[NH] = {av.x, av.y, av.z, av.w};
      float pe[NH];
      #pragma unroll
      for (int hh=0;hh<NH;hh++){
        float e = ash[hh] + ad_n[hh]; e = e>0.f?e:0.2f*e;
        pe[hh] = __expf(e - m[hh]); den[hh] += pe[hh];
      }
      const unsigned short* ts = T3 + (size_t)s*NRD + r*DIM;
      #pragma unroll
      for (int u=0;u<3;u++){
        float tv = b2f(ts[t+256*u]);
        #pragma unroll
        for (int hh=0;hh<NH;hh++) acc[u][hh] += pe[hh]*tv;
      }
    }
    #pragma unroll
    for (int hh=0;hh<NH;hh++){
      float inv = 1.0f/den[hh];
      #pragma unroll
      for (int u=0;u<3;u++) z[u][hh] += inv*acc[u][hh];
    }
  }
  #pragma unroll
  for (int u=0;u<3;u++)
    #pragma unroll
    for (int hh=0;hh<NH;hh++)
      Z[(size_t)n*HD + hh*DIM + t + 256*u] = f2b(z[u][hh]);
}

// ---------------- workspace layout ----------------------------------------------
static constexpr size_t al(size_t x){ return (x + 255) & ~(size_t)255; }
static constexpr size_t OFF_H     = 0;
static constexpr size_t OFF_HB    = OFF_H    + al((size_t)NPAD*DIM*4);
static constexpr size_t OFF_T3    = OFF_HB   + al((size_t)NPAD*DIM*2);
static constexpr size_t OFF_Z     = OFF_T3   + al((size_t)NPAD*NRD*2);
static constexpr size_t OFF_GATWS = OFF_Z    + al((size_t)NPAD*HD*2);
static constexpr size_t OFF_RELWT = OFF_GATWS+ al((size_t)NL*DIM*HD*2);
static constexpr size_t OFF_BEXT  = OFF_RELWT+ al((size_t)NR*DIM*DIM*2);
static constexpr size_t OFF_BIASX = OFF_BEXT + al((size_t)NL*NRDE*DIM*2);
static constexpr size_t OFF_W1T   = OFF_BIASX+ al((size_t)NL*NRDE*4);
static constexpr size_t OFF_W2T   = OFF_W1T  + al((size_t)512*DIM*2);
static constexpr size_t OFF_ZP    = OFF_W2T  + al((size_t)DIM*512*2);
static constexpr size_t OFF_VS    = OFF_ZP   + al((size_t)NPAD*512*2);
static constexpr size_t OFF_VD    = OFF_VS   + al((size_t)NL*DIM*NH*4);
static constexpr size_t OFF_WAS   = OFF_VD   + al((size_t)NL*DIM*NH*4);
static constexpr size_t OFF_WAD   = OFF_WAS  + al((size_t)NL*NR*DIM*NH*4);
static constexpr size_t OFF_BS    = OFF_WAD  + al((size_t)NL*NR*DIM*NH*4);
static constexpr size_t OFF_BD    = OFF_BS   + al((size_t)NL*NR*NH*4);
static constexpr size_t OFF_AS    = OFF_BD   + al((size_t)NL*NR*NH*4);
static constexpr size_t OFF_AD    = OFF_AS   + al((size_t)SCN*NH*4);
static constexpr size_t OFF_CNT   = OFF_AD   + al((size_t)SCN*NH*4);
static constexpr size_t OFF_RSTART= OFF_CNT  + al((size_t)SCN*4);
static constexpr size_t OFF_PART  = OFF_RSTART+al(((size_t)SCN+1)*4);
static constexpr size_t OFF_CUR   = OFF_PART + al(((size_t)SCB+1)*4);
static constexpr size_t OFF_CSRS  = OFF_CUR  + al((size_t)SCN*4);
static constexpr size_t OFF_CSRE  = OFF_CSRS + al((size_t)NE*4);

extern "C" void kernel_launch(void* const* d_in, const int* in_sizes, int n_in,
                              void* d_out, int out_size, void* d_ws, size_t ws_size,
                              hipStream_t stream) {
  const float* nf     = (const float*)d_in[0];
  const int*   ei     = (const int*)d_in[1];
  const int*   etype  = (const int*)d_in[2];
  const float* rel_W  = (const float*)d_in[3];
  const float* rel_b  = (const float*)d_in[4];
  const float* gat_W  = (const float*)d_in[5];
  const float* a_src  = (const float*)d_in[6];
  const float* a_dst  = (const float*)d_in[7];
  const float* gat_bias=(const float*)d_in[8];
  const float* pW1    = (const float*)d_in[9];
  const float* pb1    = (const float*)d_in[10];
  const float* pW2    = (const float*)d_in[11];
  const float* pb2    = (const float*)d_in[12];
  float* out = (float*)d_out;
  char* ws = (char*)d_ws;

  float*          H     = (float*)(ws+OFF_H);
  unsigned short* HB    = (unsigned short*)(ws+OFF_HB);
  unsigned short* T3    = (unsigned short*)(ws+OFF_T3);
  unsigned short* Z     = (unsigned short*)(ws+OFF_Z);
  unsigned short* GATWS = (unsigned short*)(ws+OFF_GATWS);
  unsigned short* RELWT = (unsigned short*)(ws+OFF_RELWT);
  unsigned short* BEXT  = (unsigned short*)(ws+OFF_BEXT);
  float*          BIASX = (float*)(ws+OFF_BIASX);
  unsigned short* W1T   = (unsigned short*)(ws+OFF_W1T);
  unsigned short* W2T   = (unsigned short*)(ws+OFF_W2T);
  unsigned short* ZP    = (unsigned short*)(ws+OFF_ZP);
  float* VS   = (float*)(ws+OFF_VS);
  float* VD   = (float*)(ws+OFF_VD);
  float* WAS  = (float*)(ws+OFF_WAS);
  float* WAD  = (float*)(ws+OFF_WAD);
  float* BS   = (float*)(ws+OFF_BS);
  float* BD   = (float*)(ws+OFF_BD);
  float* AS_  = (float*)(ws+OFF_AS);
  float* AD_  = (float*)(ws+OFF_AD);
  int* COUNTS = (int*)(ws+OFF_CNT);
  int* RSTART = (int*)(ws+OFF_RSTART);
  int* PART   = (int*)(ws+OFF_PART);
  int* CURSOR = (int*)(ws+OFF_CUR);
  int* CSRS   = (int*)(ws+OFF_CSRS);
  int* CSRE   = (int*)(ws+OFF_CSRE);

  // ---- one-time precompute ----
  k_init<<<2048,256,0,stream>>>(nf, H, HB);
  k_transpose<<<dim3(DIM/32, DIM/32, NR),256,0,stream>>>(rel_W, RELWT, DIM, DIM, (long)DIM*DIM, (long)DIM*DIM);
  k_gatws<<<dim3(DIM/32, DIM/32, NL*NH),256,0,stream>>>(gat_W, GATWS);
  k_transpose<<<dim3(512/32, DIM/32, 1),256,0,stream>>>(pW1, W1T, DIM, 512, 0, 0);
  k_transpose<<<dim3(DIM/32, 512/32, 1),256,0,stream>>>(pW2, W2T, 512, DIM, 0, 0);
  (void)hipMemsetAsync(COUNTS, 0, (size_t)SCN*4, stream);
  k_count<<<(NE+255)/256,256,0,stream>>>(etype, ei, COUNTS);
  k_scan1<<<SCB,256,0,stream>>>(COUNTS, RSTART, PART);
  k_scan2<<<1,64,0,stream>>>(PART);
  k_scan3<<<SCB,256,0,stream>>>(RSTART, PART, CURSOR);
  k_fill<<<(NE+255)/256,256,0,stream>>>(etype, ei, CURSOR, CSRS, CSRE);
  k_vsrc<<<NL*DIM/4,256,0,stream>>>(gat_W, a_src, a_dst, VS, VD);
  k_wa<<<NL*NR*DIM/4,256,0,stream>>>(rel_W, VS, VD, WAS, WAD);
  k_bsd<<<1,64,0,stream>>>(rel_b, VS, VD, BS, BD);
  // per-layer extended B: [RELWT | alpha weight rows]
  for (int l=0; l<NL; l++)
    (void)hipMemcpyAsync(BEXT + (size_t)l*NRDE*DIM, RELWT, (size_t)NRD*DIM*2,
                         hipMemcpyDeviceToDevice, stream);
  k_bext<<<(NL*128*DIM+255)/256,256,0,stream>>>(WAS, WAD, BEXT);
  k_biasx<<<(NL*NRDE+255)/256,256,0,stream>>>(rel_b, BS, BD, BIASX);

  // ---- layers ----
  for (int l=0; l<NL; l++){
    // T3[n][r*768+q] (+ fused alpha columns -> AS_/AD_)
    gemmU<4><<<dim3(NRDE/128, NPAD/128),512,0,stream>>>(
        HB, BEXT + (size_t)l*NRDE*DIM, T3, nullptr, nullptr,
        BIASX + (size_t)l*NRDE, 1.0f, DIM, NN, NRD, AS_, AD_);
    k_aggz<<<NN,256,0,stream>>>(T3, AS_, AD_, RSTART, CSRS, Z);
    // h = relu(h + Z @ GATWS[l] + 3*gat_bias[l]); HB = bf16(h)
    float* hw = (l==NL-1) ? (out + (size_t)NN*DIM) : H;
    gemmU<3><<<dim3(DIM/128, NPAD/128),512,0,stream>>>(
        Z, GATWS + (size_t)l*DIM*HD, hw, HB, H, gat_bias + (size_t)l*DIM, 3.0f, HD, NN, DIM,
        nullptr, nullptr);
  }

  // ---- final projection ----
  gemmU<2><<<dim3(512/128, NPAD/128),512,0,stream>>>(
      HB, W1T, ZP, nullptr, nullptr, pb1, 1.0f, DIM, NN, 512, nullptr, nullptr);
  gemmU<0><<<dim3(DIM/128, NPAD/128),512,0,stream>>>(
      ZP, W2T, out, nullptr, nullptr, pb2, 1.0f, 512, NN, DIM, nullptr, nullptr);
}

// Round 18
// 780.777 us; speedup vs baseline: 1.0649x; 1.0649x over previous
//
#include <hip/hip_runtime.h>
#include <stdint.h>

#define NN 10000
#define NE 48000
#define DIM 768
#define NH 4
#define NL 4
#define NR 3
#define HD 3072
#define NPAD 10240   // 80*128
#define NRD (NR*DIM) // 2304
#define NRDE 2432    // 19*128 (T3 cols + 128 alpha cols)
#define SCN (NR*NN)  // 30000
#define SCB ((SCN+255)/256) // 118

typedef __attribute__((ext_vector_type(8))) short bf16x8;
typedef __attribute__((ext_vector_type(4))) float f32x4;

__device__ __forceinline__ unsigned short f2b(float f){
  union {float f; unsigned u;} v; v.f=f;
  unsigned r = v.u + 0x7FFFu + ((v.u>>16)&1u);
  return (unsigned short)(r>>16);
}
__device__ __forceinline__ float b2f(unsigned short b){
  union {unsigned u; float f;} v; v.u = ((unsigned)b)<<16; return v.f;
}

__device__ __forceinline__ void gl_lds16(const void* g, void* l){
  __builtin_amdgcn_global_load_lds(
    reinterpret_cast<const __attribute__((address_space(1))) uint32_t*>(reinterpret_cast<uintptr_t>(g)),
    reinterpret_cast<__attribute__((address_space(3))) uint32_t*>(reinterpret_cast<uintptr_t>(l)),
    16, 0, 0);
}

// ====== 128x128 8-wave GEMM, 2-barrier/tile (round-16 proven, 826 us) ==========
// C[m][n] = sum_k A[m][k]*Bt[n][k]; A,Bt bf16 K-contiguous; f32 accum.
// MODE: 0 = f32 out (+bias), 1 = bf16 out (+bias), 2 = bf16 relu (+bias),
//       3 = fused update: w=relu(RH+acc+bscale*bias); C=w(f32), C2=bf16(w)
//       4 = T3+alpha: col<NRD -> bf16 C; col-NRD<24 -> f32 scatter to PA/PD
template<int MODE>
__global__ __launch_bounds__(512, 4)
void gemmU(const unsigned short* __restrict__ A, const unsigned short* __restrict__ Bt,
           void* __restrict__ C, unsigned short* __restrict__ C2,
           const float* __restrict__ RH, const float* __restrict__ bias, float bscale,
           int K, int Mvalid, int ldc,
           float* __restrict__ PA, float* __restrict__ PD)
{
  constexpr int NB     = 2;
  constexpr int ABYTES = 16384;
  constexpr int SLOT   = 32768;
  __shared__ char lds2[2*SLOT];            // 64 KB -> 2 blocks/CU

  const int tid = threadIdx.x;
  const int lane = tid & 63;
  const int wv = tid >> 6;
  const int wr = wv >> 2;
  const int wc = wv & 3;
  const int fr = lane & 15;
  const int fs = lane >> 4;

  int bx, by;
  {
    int fid = blockIdx.y * gridDim.x + blockIdx.x;
    if ((gridDim.y & 7) == 0){
      int xcd = fid & 7, slot = fid >> 3;
      bx = slot % gridDim.x;
      by = (slot / gridDim.x) * 8 + xcd;
    } else { bx = blockIdx.x; by = blockIdx.y; }
  }

  const unsigned short* Ag = A + (size_t)by * 128 * K;
  const unsigned short* Bg = Bt + (size_t)bx * 128 * K;
  const int T = K >> 6;

  f32x4 acc[4][NB];
  #pragma unroll
  for (int i=0;i<4;i++)
    #pragma unroll
    for (int j=0;j<NB;j++) acc[i][j] = (f32x4){0.f,0.f,0.f,0.f};

  auto stage = [&](int t2, int c){
    char* region = lds2 + (t2 & 1) * SLOT;
    const unsigned short* G = Ag;
    int off = c * 8192 + tid * 16;
    if (c >= 2){ G = Bg; off -= ABYTES; region += ABYTES; }
    int row = off >> 7;
    int srcslot = ((off >> 4) & 7) ^ (row & 7);
    gl_lds16((const char*)(G + (size_t)row * K + (size_t)t2 * 64) + (srcslot << 4),
             region + off);
  };

  // prologue: A(0),B(0) then A(1)  -> 6 outstanding, newest 2 = A(1)
  #pragma unroll
  for (int c=0;c<4;c++) stage(0,c);
  __builtin_amdgcn_sched_barrier(0);
  stage(1,0); stage(1,1);
  __builtin_amdgcn_sched_barrier(0);

  for (int t=0; t<T; ++t){
    const char* As_ = lds2 + (t&1)*SLOT;
    const char* Bs_ = As_ + ABYTES;

    if (t < T-1) asm volatile("s_waitcnt vmcnt(2)" ::: "memory");
    else         asm volatile("s_waitcnt vmcnt(0)" ::: "memory");
    __builtin_amdgcn_s_barrier();

    // issue all 12 fragment reads
    bf16x8 a[4][2], b[NB][2];
    #pragma unroll
    for (int ni=0; ni<NB; ni++){
      const int row = wc*32 + ni*16 + fr;
      #pragma unroll
      for (int ks=0; ks<2; ks++){
        const int bo = row*128 + ((((ks<<2)+fs) ^ (row&7))<<4);
        b[ni][ks] = *(const bf16x8*)(Bs_ + bo);
      }
    }
    #pragma unroll
    for (int mi=0; mi<4; mi++){
      const int row = wr*64 + mi*16 + fr;
      #pragma unroll
      for (int ks=0; ks<2; ks++){
        const int bo = row*128 + ((((ks<<2)+fs) ^ (row&7))<<4);
        a[mi][ks] = *(const bf16x8*)(As_ + bo);
      }
    }
    asm volatile("s_waitcnt lgkmcnt(0)" ::: "memory");
    __builtin_amdgcn_s_barrier();            // all waves done reading this slot

    if (t+1 < T){ stage(t+1, 2); stage(t+1, 3); }   // B(t+1) -> other slot
    if (t+2 < T){ stage(t+2, 0); stage(t+2, 1); }   // A(t+2) -> this slot
    __builtin_amdgcn_sched_barrier(0);

    __builtin_amdgcn_s_setprio(1);
    #pragma unroll
    for (int mi=0; mi<4; mi++)
      #pragma unroll
      for (int ni=0; ni<NB; ni++)
        #pragma unroll
        for (int ks=0; ks<2; ks++)
          acc[mi][ni] = __builtin_amdgcn_mfma_f32_16x16x32_bf16(
              a[mi][ks], b[ni][ks], acc[mi][ni], 0,0,0);
    __builtin_amdgcn_s_setprio(0);
  }

  const int cr = (lane>>4)<<2, cc = lane&15;
  #pragma unroll
  for (int mi=0; mi<4; mi++){
    #pragma unroll
    for (int ni=0; ni<NB; ni++){
      const int col = bx*128 + wc*32 + ni*16 + cc;
      const float bv = bias ? bscale*bias[col] : 0.0f;
      #pragma unroll
      for (int j=0; j<4; j++){
        const int row = by*128 + wr*64 + mi*16 + cr + j;
        if (row < Mvalid){
          const size_t o = (size_t)row*ldc + col;
          float v = acc[mi][ni][j] + bv;
          if (MODE==2) v = v>0.f?v:0.f;
          if (MODE==0)      ((float*)C)[o] = v;
          else if (MODE==1 || MODE==2) ((unsigned short*)C)[o] = f2b(v);
          else if (MODE==3){
            float w = RH[o] + v;
            w = w>0.f?w:0.f;
            ((float*)C)[o] = w; C2[o] = f2b(w);
          } else { // MODE==4
            if (col < NRD) ((unsigned short*)C)[o] = f2b(v);
            else {
              int jj = col - NRD;
              if (jj < 24){
                int rr = jj>>3, hh = (jj>>1)&3, ss = jj&1;
                float* dst = ss ? PD : PA;
                dst[((size_t)rr*NN + row)*NH + hh] = v;
              }
            }
          }
        }
      }
    }
  }
}

// ---------------- misc elementwise / precompute --------------------------------
__global__ void k_init(const float* __restrict__ nf, float* __restrict__ h, unsigned short* __restrict__ hb){
  for (size_t i = (size_t)blockIdx.x*256+threadIdx.x; i < (size_t)NPAD*DIM; i += (size_t)gridDim.x*256){
    float v = (i < (size_t)NN*DIM) ? nf[i] : 0.0f;
    h[i]=v; hb[i]=f2b(v);
  }
}
__global__ void k_transpose(const float* __restrict__ in, unsigned short* __restrict__ out,
                            int rows, int cols, long in_bs, long out_bs){
  __shared__ float tile[32][33];
  int b = blockIdx.z;
  int r0 = blockIdx.y*32, c0 = blockIdx.x*32;
  int tx = threadIdx.x & 31, ty = threadIdx.x >> 5;
  const float* ip = in + (size_t)b*in_bs;
  unsigned short* op = out + (size_t)b*out_bs;
  #pragma unroll
  for (int i=ty;i<32;i+=8) tile[i][tx] = ip[(size_t)(r0+i)*cols + c0+tx];
  __syncthreads();
  #pragma unroll
  for (int i=ty;i<32;i+=8) op[(size_t)(c0+i)*rows + r0+tx] = f2b(tile[tx][i]);
}
// GATWS[l][d][h*768+q] = 0.25 * gat_W[l][q][h*768+d]
__global__ void k_gatws(const float* __restrict__ gat_W, unsigned short* __restrict__ out){
  __shared__ float tile[32][33];
  int z = blockIdx.z; int l = z>>2, h = z&3;
  size_t base = (size_t)l*DIM*HD + (size_t)h*DIM;
  int r0 = blockIdx.y*32, c0 = blockIdx.x*32;
  int tx = threadIdx.x & 31, ty = threadIdx.x >> 5;
  #pragma unroll
  for (int i=ty;i<32;i+=8) tile[i][tx] = gat_W[base + (size_t)(r0+i)*HD + c0+tx];
  __syncthreads();
  #pragma unroll
  for (int i=ty;i<32;i+=8) out[base + (size_t)(c0+i)*HD + r0+tx] = f2b(0.25f*tile[tx][i]);
}

// attention-weight precompute
__global__ __launch_bounds__(256) void k_vsrc(const float* __restrict__ gat_W, const float* __restrict__ a_src,
                       const float* __restrict__ a_dst, float* __restrict__ vs, float* __restrict__ vd){
  int gw = blockIdx.x*4 + (threadIdx.x>>6);
  if (gw >= NL*DIM) return;
  int l = gw/DIM;
  int lane = threadIdx.x & 63;
  const float* grow = gat_W + (size_t)gw*HD;
  #pragma unroll
  for (int h=0;h<NH;h++){
    const float* asr = a_src + ((size_t)l*NH + h)*DIM;
    const float* adr = a_dst + ((size_t)l*NH + h)*DIM;
    float s=0.f,d=0.f;
    for (int dd=lane; dd<DIM; dd+=64){
      float gv = grow[h*DIM+dd];
      s += gv*asr[dd]; d += gv*adr[dd];
    }
    #pragma unroll
    for (int o=32;o>=1;o>>=1){ s += __shfl_xor(s,o,64); d += __shfl_xor(d,o,64); }
    if (lane==0){ vs[(size_t)gw*NH+h]=s; vd[(size_t)gw*NH+h]=d; }
  }
}
__global__ __launch_bounds__(256) void k_wa(const float* __restrict__ rel_W, const float* __restrict__ vs,
                     const float* __restrict__ vd, float* __restrict__ was, float* __restrict__ wad){
  int gw = blockIdx.x*4 + (threadIdx.x>>6);
  if (gw >= NL*NR*DIM) return;
  int lr = gw/DIM, k = gw%DIM;
  int l = lr/NR, r = lr%NR;
  int lane = threadIdx.x & 63;
  const float* wrow = rel_W + ((size_t)r*DIM + k)*DIM;
  float s0=0,s1=0,s2=0,s3=0,d0=0,d1=0,d2=0,d3=0;
  for (int q=lane; q<DIM; q+=64){
    float w = wrow[q];
    const float4 v1 = *(const float4*)(vs + ((size_t)l*DIM+q)*NH);
    const float4 v2 = *(const float4*)(vd + ((size_t)l*DIM+q)*NH);
    s0+=w*v1.x; s1+=w*v1.y; s2+=w*v1.z; s3+=w*v1.w;
    d0+=w*v2.x; d1+=w*v2.y; d2+=w*v2.z; d3+=w*v2.w;
  }
  #pragma unroll
  for (int o=32;o>=1;o>>=1){
    s0+=__shfl_xor(s0,o,64); s1+=__shfl_xor(s1,o,64); s2+=__shfl_xor(s2,o,64); s3+=__shfl_xor(s3,o,64);
    d0+=__shfl_xor(d0,o,64); d1+=__shfl_xor(d1,o,64); d2+=__shfl_xor(d2,o,64); d3+=__shfl_xor(d3,o,64);
  }
  if (lane==0){
    float4* ps = (float4*)(was + (size_t)gw*NH); *ps = make_float4(s0,s1,s2,s3);
    float4* pd = (float4*)(wad + (size_t)gw*NH); *pd = make_float4(d0,d1,d2,d3);
  }
}
__global__ void k_bsd(const float* __restrict__ rel_b, const float* __restrict__ vs, const float* __restrict__ vd,
                      float* __restrict__ bs, float* __restrict__ bd){
  int t = threadIdx.x; if (t >= NL*NR*NH) return;
  int l = t/(NR*NH), r = (t/NH)%NR, h = t%NH;
  float s=0.f,d=0.f;
  for (int q=0;q<DIM;q++){
    float b = rel_b[r*DIM+q];
    s += b*vs[((size_t)l*DIM+q)*NH+h];
    d += b*vd[((size_t)l*DIM+q)*NH+h];
  }
  bs[t]=s; bd[t]=d;
}
// BEXT alpha rows: BEXT[l][NRD+j][k], j<24 -> (s?WAD:WAS)[l,r,k,h]; j>=24 -> 0
__global__ void k_bext(const float* __restrict__ WAS, const float* __restrict__ WAD,
                       unsigned short* __restrict__ BEXT){
  int idx = blockIdx.x*256+threadIdx.x;
  if (idx >= NL*128*DIM) return;
  int l = idx/(128*DIM);
  int rem = idx - l*(128*DIM);
  int j = rem/DIM, k = rem%DIM;
  float v = 0.f;
  if (j < 24){
    int r = j>>3, h = (j>>1)&3, s = j&1;
    const float* src = s ? WAD : WAS;
    v = src[(((size_t)l*NR+r)*DIM + k)*NH + h];
  }
  BEXT[(size_t)l*NRDE*DIM + (size_t)(NRD+j)*DIM + k] = f2b(v);
}
// BIASX[l][c]: c<NRD -> rel_b[c]; NRD+j (j<24) -> (s?BD:BS)[l,r,h]; else 0
__global__ void k_biasx(const float* __restrict__ rel_b, const float* __restrict__ BS,
                        const float* __restrict__ BD, float* __restrict__ BIASX){
  int idx = blockIdx.x*256+threadIdx.x;
  if (idx >= NL*NRDE) return;
  int l = idx/NRDE, c = idx%NRDE;
  float v = 0.f;
  if (c < NRD) v = rel_b[c];
  else {
    int j = c-NRD;
    if (j < 24){
      int r = j>>3, h = (j>>1)&3, s = j&1;
      v = (s ? BD : BS)[(l*NR+r)*NH + h];
    }
  }
  BIASX[idx] = v;
}

// ---------------- CSR build ----------------------------------------------------
__global__ void k_count(const int* __restrict__ et, const int* __restrict__ ei, int* __restrict__ counts){
  int e = blockIdx.x*256+threadIdx.x; if (e>=NE) return;
  atomicAdd(&counts[et[e]*NN + ei[NE+e]], 1);
}
__global__ void k_scan1(const int* __restrict__ counts, int* __restrict__ excl, int* __restrict__ part){
  __shared__ int tmp[256];
  int b = blockIdx.x, t = threadIdx.x, idx = b*256+t;
  int v = (idx<SCN)? counts[idx] : 0;
  tmp[t]=v; __syncthreads();
  #pragma unroll
  for (int off=1; off<256; off<<=1){
    int x = (t>=off)? tmp[t-off] : 0;
    __syncthreads(); tmp[t]+=x; __syncthreads();
  }
  if (idx<SCN) excl[idx] = tmp[t]-v;
  if (t==255) part[b] = tmp[255];
}
__global__ void k_scan2(int* __restrict__ part){
  if (threadIdx.x==0){
    int c=0;
    for (int i=0;i<SCB;i++){ int v=part[i]; part[i]=c; c+=v; }
    part[SCB]=c;
  }
}
__global__ void k_scan3(int* __restrict__ rs, const int* __restrict__ part, int* __restrict__ cursor){
  int b = blockIdx.x, idx = b*256+threadIdx.x;
  if (idx<SCN){
    int e = rs[idx] + part[b];
    rs[idx]=e; cursor[idx]=e;
  }
  if (idx==0) rs[SCN] = part[SCB];
}
__global__ void k_fill(const int* __restrict__ et, const int* __restrict__ ei, int* __restrict__ cursor,
                       int* __restrict__ csrs, int* __restrict__ csre){
  int e = blockIdx.x*256+threadIdx.x; if (e>=NE) return;
  int pos = atomicAdd(&cursor[et[e]*NN + ei[NE+e]], 1);
  csrs[pos] = ei[e];
  csre[pos] = e;
}

// ---------------- fused softmax + aggregate (single-pass, no max) --------------
// softmax is shift-invariant; |e| << 60 in-regime so exp(e) is f32-safe.
// Z[n][h*768+q] = sum_r (1/den_{r,h}) * ( p_self t_r[n][q] + sum_e p_eh t_r[s][q] )
__global__ __launch_bounds__(256) void k_aggz(const unsigned short* __restrict__ T3,
    const float* __restrict__ aS, const float* __restrict__ aD,
    const int* __restrict__ row_start, const int* __restrict__ csrs,
    unsigned short* __restrict__ Z)
{
  int n = blockIdx.x, t = threadIdx.x;
  float z[3][NH];
  #pragma unroll
  for (int u=0;u<3;u++)
    #pragma unroll
    for (int hh=0;hh<NH;hh++) z[u][hh]=0.f;

  for (int r=0;r<NR;r++){
    int rn = r*NN+n;
    const float4 adv = *(const float4*)(aD + (size_t)rn*NH);
    const float4 asv = *(const float4*)(aS + (size_t)rn*NH);
    const float ad_n[NH] = {adv.x, adv.y, adv.z, adv.w};
    float den[NH], acc[3][NH];
    const unsigned short* tn = T3 + (size_t)n*NRD + r*DIM;
    {
      const float as_n[NH] = {asv.x, asv.y, asv.z, asv.w};
      float ps[NH];
      #pragma unroll
      for (int hh=0;hh<NH;hh++){
        float e = as_n[hh] + ad_n[hh]; e = e>0.f?e:0.2f*e;
        ps[hh] = __expf(fminf(e, 60.0f)); den[hh]=ps[hh];
      }
      #pragma unroll
      for (int u=0;u<3;u++){
        float tv = b2f(tn[t+256*u]);
        #pragma unroll
        for (int hh=0;hh<NH;hh++) acc[u][hh] = ps[hh]*tv;
      }
    }
    int beg = row_start[rn], end = row_start[rn+1];
    for (int p=beg;p<end;p++){
      int s = csrs[p];
      const float4 av = *(const float4*)(aS + ((size_t)r*NN+s)*NH);
      const float ash[NH] = {av.x, av.y, av.z, av.w};
      float pe[NH];
      #pragma unroll
      for (int hh=0;hh<NH;hh++){
        float e = ash[hh] + ad_n[hh]; e = e>0.f?e:0.2f*e;
        pe[hh] = __expf(fminf(e, 60.0f)); den[hh] += pe[hh];
      }
      const unsigned short* ts = T3 + (size_t)s*NRD + r*DIM;
      #pragma unroll
      for (int u=0;u<3;u++){
        float tv = b2f(ts[t+256*u]);
        #pragma unroll
        for (int hh=0;hh<NH;hh++) acc[u][hh] += pe[hh]*tv;
      }
    }
    #pragma unroll
    for (int hh=0;hh<NH;hh++){
      float inv = 1.0f/den[hh];
      #pragma unroll
      for (int u=0;u<3;u++) z[u][hh] += inv*acc[u][hh];
    }
  }
  #pragma unroll
  for (int u=0;u<3;u++)
    #pragma unroll
    for (int hh=0;hh<NH;hh++)
      Z[(size_t)n*HD + hh*DIM + t + 256*u] = f2b(z[u][hh]);
}

// ---------------- workspace layout ----------------------------------------------
static constexpr size_t al(size_t x){ return (x + 255) & ~(size_t)255; }
static constexpr size_t OFF_H     = 0;
static constexpr size_t OFF_HB    = OFF_H    + al((size_t)NPAD*DIM*4);
static constexpr size_t OFF_T3    = OFF_HB   + al((size_t)NPAD*DIM*2);
static constexpr size_t OFF_Z     = OFF_T3   + al((size_t)NPAD*NRD*2);
static constexpr size_t OFF_GATWS = OFF_Z    + al((size_t)NPAD*HD*2);
static constexpr size_t OFF_RELWT = OFF_GATWS+ al((size_t)NL*DIM*HD*2);
static constexpr size_t OFF_BEXT  = OFF_RELWT+ al((size_t)NR*DIM*DIM*2);
static constexpr size_t OFF_BIASX = OFF_BEXT + al((size_t)NL*NRDE*DIM*2);
static constexpr size_t OFF_W1T   = OFF_BIASX+ al((size_t)NL*NRDE*4);
static constexpr size_t OFF_W2T   = OFF_W1T  + al((size_t)512*DIM*2);
static constexpr size_t OFF_ZP    = OFF_W2T  + al((size_t)DIM*512*2);
static constexpr size_t OFF_VS    = OFF_ZP   + al((size_t)NPAD*512*2);
static constexpr size_t OFF_VD    = OFF_VS   + al((size_t)NL*DIM*NH*4);
static constexpr size_t OFF_WAS   = OFF_VD   + al((size_t)NL*DIM*NH*4);
static constexpr size_t OFF_WAD   = OFF_WAS  + al((size_t)NL*NR*DIM*NH*4);
static constexpr size_t OFF_BS    = OFF_WAD  + al((size_t)NL*NR*DIM*NH*4);
static constexpr size_t OFF_BD    = OFF_BS   + al((size_t)NL*NR*NH*4);
static constexpr size_t OFF_AS    = OFF_BD   + al((size_t)NL*NR*NH*4);
static constexpr size_t OFF_AD    = OFF_AS   + al((size_t)SCN*NH*4);
static constexpr size_t OFF_CNT   = OFF_AD   + al((size_t)SCN*NH*4);
static constexpr size_t OFF_RSTART= OFF_CNT  + al((size_t)SCN*4);
static constexpr size_t OFF_PART  = OFF_RSTART+al(((size_t)SCN+1)*4);
static constexpr size_t OFF_CUR   = OFF_PART + al(((size_t)SCB+1)*4);
static constexpr size_t OFF_CSRS  = OFF_CUR  + al((size_t)SCN*4);
static constexpr size_t OFF_CSRE  = OFF_CSRS + al((size_t)NE*4);

extern "C" void kernel_launch(void* const* d_in, const int* in_sizes, int n_in,
                              void* d_out, int out_size, void* d_ws, size_t ws_size,
                              hipStream_t stream) {
  const float* nf     = (const float*)d_in[0];
  const int*   ei     = (const int*)d_in[1];
  const int*   etype  = (const int*)d_in[2];
  const float* rel_W  = (const float*)d_in[3];
  const float* rel_b  = (const float*)d_in[4];
  const float* gat_W  = (const float*)d_in[5];
  const float* a_src  = (const float*)d_in[6];
  const float* a_dst  = (const float*)d_in[7];
  const float* gat_bias=(const float*)d_in[8];
  const float* pW1    = (const float*)d_in[9];
  const float* pb1    = (const float*)d_in[10];
  const float* pW2    = (const float*)d_in[11];
  const float* pb2    = (const float*)d_in[12];
  float* out = (float*)d_out;
  char* ws = (char*)d_ws;

  float*          H     = (float*)(ws+OFF_H);
  unsigned short* HB    = (unsigned short*)(ws+OFF_HB);
  unsigned short* T3    = (unsigned short*)(ws+OFF_T3);
  unsigned short* Z     = (unsigned short*)(ws+OFF_Z);
  unsigned short* GATWS = (unsigned short*)(ws+OFF_GATWS);
  unsigned short* RELWT = (unsigned short*)(ws+OFF_RELWT);
  unsigned short* BEXT  = (unsigned short*)(ws+OFF_BEXT);
  float*          BIASX = (float*)(ws+OFF_BIASX);
  unsigned short* W1T   = (unsigned short*)(ws+OFF_W1T);
  unsigned short* W2T   = (unsigned short*)(ws+OFF_W2T);
  unsigned short* ZP    = (unsigned short*)(ws+OFF_ZP);
  float* VS   = (float*)(ws+OFF_VS);
  float* VD   = (float*)(ws+OFF_VD);
  float* WAS  = (float*)(ws+OFF_WAS);
  float* WAD  = (float*)(ws+OFF_WAD);
  float* BS   = (float*)(ws+OFF_BS);
  float* BD   = (float*)(ws+OFF_BD);
  float* AS_  = (float*)(ws+OFF_AS);
  float* AD_  = (float*)(ws+OFF_AD);
  int* COUNTS = (int*)(ws+OFF_CNT);
  int* RSTART = (int*)(ws+OFF_RSTART);
  int* PART   = (int*)(ws+OFF_PART);
  int* CURSOR = (int*)(ws+OFF_CUR);
  int* CSRS   = (int*)(ws+OFF_CSRS);
  int* CSRE   = (int*)(ws+OFF_CSRE);

  // ---- one-time precompute ----
  k_init<<<2048,256,0,stream>>>(nf, H, HB);
  k_transpose<<<dim3(DIM/32, DIM/32, NR),256,0,stream>>>(rel_W, RELWT, DIM, DIM, (long)DIM*DIM, (long)DIM*DIM);
  k_gatws<<<dim3(DIM/32, DIM/32, NL*NH),256,0,stream>>>(gat_W, GATWS);
  k_transpose<<<dim3(512/32, DIM/32, 1),256,0,stream>>>(pW1, W1T, DIM, 512, 0, 0);
  k_transpose<<<dim3(DIM/32, 512/32, 1),256,0,stream>>>(pW2, W2T, 512, DIM, 0, 0);
  (void)hipMemsetAsync(COUNTS, 0, (size_t)SCN*4, stream);
  k_count<<<(NE+255)/256,256,0,stream>>>(etype, ei, COUNTS);
  k_scan1<<<SCB,256,0,stream>>>(COUNTS, RSTART, PART);
  k_scan2<<<1,64,0,stream>>>(PART);
  k_scan3<<<SCB,256,0,stream>>>(RSTART, PART, CURSOR);
  k_fill<<<(NE+255)/256,256,0,stream>>>(etype, ei, CURSOR, CSRS, CSRE);
  k_vsrc<<<NL*DIM/4,256,0,stream>>>(gat_W, a_src, a_dst, VS, VD);
  k_wa<<<NL*NR*DIM/4,256,0,stream>>>(rel_W, VS, VD, WAS, WAD);
  k_bsd<<<1,64,0,stream>>>(rel_b, VS, VD, BS, BD);
  // per-layer extended B: [RELWT | alpha weight rows]
  for (int l=0; l<NL; l++)
    (void)hipMemcpyAsync(BEXT + (size_t)l*NRDE*DIM, RELWT, (size_t)NRD*DIM*2,
                         hipMemcpyDeviceToDevice, stream);
  k_bext<<<(NL*128*DIM+255)/256,256,0,stream>>>(WAS, WAD, BEXT);
  k_biasx<<<(NL*NRDE+255)/256,256,0,stream>>>(rel_b, BS, BD, BIASX);

  // ---- layers ----
  for (int l=0; l<NL; l++){
    // T3[n][r*768+q] (+ fused alpha columns -> AS_/AD_)
    gemmU<4><<<dim3(NRDE/128, NPAD/128),512,0,stream>>>(
        HB, BEXT + (size_t)l*NRDE*DIM, T3, nullptr, nullptr,
        BIASX + (size_t)l*NRDE, 1.0f, DIM, NN, NRD, AS_, AD_);
    k_aggz<<<NN,256,0,stream>>>(T3, AS_, AD_, RSTART, CSRS, Z);
    // h = relu(h + Z @ GATWS[l] + 3*gat_bias[l]); HB = bf16(h)
    float* hw = (l==NL-1) ? (out + (size_t)NN*DIM) : H;
    gemmU<3><<<dim3(DIM/128, NPAD/128),512,0,stream>>>(
        Z, GATWS + (size_t)l*DIM*HD, hw, HB, H, gat_bias + (size_t)l*DIM, 3.0f, HD, NN, DIM,
        nullptr, nullptr);
  }

  // ---- final projection ----
  gemmU<2><<<dim3(512/128, NPAD/128),512,0,stream>>>(
      HB, W1T, ZP, nullptr, nullptr, pb1, 1.0f, DIM, NN, 512, nullptr, nullptr);
  gemmU<0><<<dim3(DIM/128, NPAD/128),512,0,stream>>>(
      ZP, W2T, out, nullptr, nullptr, pb2, 1.0f, 512, NN, DIM, nullptr, nullptr);
}